// Round 1
// baseline (20660.455 us; speedup 1.0000x reference)
//
#include <hip/hip_runtime.h>
#include <math.h>

#define B_  50
#define T_  512
#define I_  1024
#define H_  512
#define NG_ 2048
#define BP  64   // padded batch stride for transposed state buffers

__device__ __forceinline__ float sigmf(float x) {
    return 1.0f / (1.0f + __expf(-x));
}
// overflow-safe tanh via e^{-2|x|} in (0,1]
__device__ __forceinline__ float tanh_fast(float x) {
    float ax = fabsf(x);
    float e  = __expf(-2.0f * ax);
    float t  = (1.0f - e) / (1.0f + e);
    return copysignf(t, x);
}

// ---------------------------------------------------------------------------
// C[m][n] = bias[n] + sum_k A[m][k] * W[n][k]
// 128x128 tile, K-step 16, 256 threads, 8x8 accum per thread. M,N % 128 == 0,
// K % 16 == 0.
// ---------------------------------------------------------------------------
__global__ __launch_bounds__(256) void gemm_bias(
    const float* __restrict__ A, const float* __restrict__ W,
    const float* __restrict__ bias, float* __restrict__ C,
    int M, int N, int K) {
    __shared__ float As[16][132];
    __shared__ float Ws[16][132];
    const int tid = threadIdx.x;
    const int m0 = blockIdx.y * 128, n0 = blockIdx.x * 128;
    const int lr = tid >> 2;            // 0..63 tile row
    const int lk = (tid & 3) << 2;      // 0,4,8,12 k offset
    const int tx = tid & 15, ty = tid >> 4;

    float acc[8][8];
#pragma unroll
    for (int i = 0; i < 8; ++i)
#pragma unroll
        for (int j = 0; j < 8; ++j) acc[i][j] = 0.0f;

    for (int k0 = 0; k0 < K; k0 += 16) {
        float4 a0 = *(const float4*)(A + (size_t)(m0 + lr) * K + k0 + lk);
        float4 a1 = *(const float4*)(A + (size_t)(m0 + lr + 64) * K + k0 + lk);
        float4 w0 = *(const float4*)(W + (size_t)(n0 + lr) * K + k0 + lk);
        float4 w1 = *(const float4*)(W + (size_t)(n0 + lr + 64) * K + k0 + lk);
        __syncthreads();
        As[lk + 0][lr] = a0.x; As[lk + 1][lr] = a0.y; As[lk + 2][lr] = a0.z; As[lk + 3][lr] = a0.w;
        As[lk + 0][lr + 64] = a1.x; As[lk + 1][lr + 64] = a1.y; As[lk + 2][lr + 64] = a1.z; As[lk + 3][lr + 64] = a1.w;
        Ws[lk + 0][lr] = w0.x; Ws[lk + 1][lr] = w0.y; Ws[lk + 2][lr] = w0.z; Ws[lk + 3][lr] = w0.w;
        Ws[lk + 0][lr + 64] = w1.x; Ws[lk + 1][lr + 64] = w1.y; Ws[lk + 2][lr + 64] = w1.z; Ws[lk + 3][lr + 64] = w1.w;
        __syncthreads();
#pragma unroll
        for (int k = 0; k < 16; ++k) {
            const float4 av0 = *(const float4*)&As[k][tx * 4];
            const float4 av1 = *(const float4*)&As[k][64 + tx * 4];
            const float4 bv0 = *(const float4*)&Ws[k][ty * 4];
            const float4 bv1 = *(const float4*)&Ws[k][64 + ty * 4];
            float a[8] = {av0.x, av0.y, av0.z, av0.w, av1.x, av1.y, av1.z, av1.w};
            float b[8] = {bv0.x, bv0.y, bv0.z, bv0.w, bv1.x, bv1.y, bv1.z, bv1.w};
#pragma unroll
            for (int i = 0; i < 8; ++i)
#pragma unroll
                for (int j = 0; j < 8; ++j) acc[i][j] = fmaf(a[i], b[j], acc[i][j]);
        }
    }

    const float4 bv0 = *(const float4*)&bias[n0 + ty * 4];
    const float4 bv1 = *(const float4*)&bias[n0 + 64 + ty * 4];
    const float bb[8] = {bv0.x, bv0.y, bv0.z, bv0.w, bv1.x, bv1.y, bv1.z, bv1.w};
#pragma unroll
    for (int i = 0; i < 8; ++i) {
        int m = m0 + ((i < 4) ? (tx * 4 + i) : (64 + tx * 4 + (i - 4)));
        float4 v0, v1;
        v0.x = acc[i][0] + bb[0]; v0.y = acc[i][1] + bb[1];
        v0.z = acc[i][2] + bb[2]; v0.w = acc[i][3] + bb[3];
        v1.x = acc[i][4] + bb[4]; v1.y = acc[i][5] + bb[5];
        v1.z = acc[i][6] + bb[6]; v1.w = acc[i][7] + bb[7];
        *(float4*)&C[(size_t)m * N + n0 + ty * 4] = v0;
        *(float4*)&C[(size_t)m * N + n0 + 64 + ty * 4] = v1;
    }
}

// ---------------------------------------------------------------------------
// state init: hT[j][b] = h0[b][j] (b<50 else 0), same for cT
// ---------------------------------------------------------------------------
__global__ void init_state(const float* __restrict__ h0, const float* __restrict__ c0,
                           float* __restrict__ hT, float* __restrict__ cT) {
    int idx = blockIdx.x * blockDim.x + threadIdx.x;
    if (idx >= H_ * BP) return;
    int j = idx >> 6, b = idx & 63;
    float hv = (b < B_) ? h0[b * H_ + j] : 0.0f;
    float cv = (b < B_) ? c0[b * H_ + j] : 0.0f;
    hT[idx] = hv;
    cT[idx] = cv;
}

// ---------------------------------------------------------------------------
// One LSTM time step. 256 blocks; block bi owns h-components j0=2*bi, j0+1,
// i.e. 8 gate rows (i,f,g,o x 2). W_hh slice in LDS (16 KB), all 50 batches
// handled per block so W is read once per step. hT layout [k][BP] so the 32
// batch lanes make 128B coalesced reads.
// ---------------------------------------------------------------------------
__global__ __launch_bounds__(256) void lstm_step(
    const float* __restrict__ xg,     // [B][T][NG], bias already included
    const float* __restrict__ hT_in,  // [H][BP]
    float* __restrict__ hT_out,       // [H][BP]
    float* __restrict__ cT,           // [H][BP]
    const float* __restrict__ W_hh,   // [NG][H]
    float* __restrict__ hs,           // [B][T][H] or nullptr
    int t) {
    __shared__ float w_lds[8][H_];    // 16 KB
    __shared__ float g_lds[8][BP];    // 2 KB
    const int tid = threadIdx.x;
    const int j0 = blockIdx.x * 2;

    // stage 8 W_hh rows -> LDS (coalesced float4)
#pragma unroll
    for (int it = 0; it < 4; ++it) {
        int idx = tid + it * 256;          // float4 index, 0..1023
        int r = idx >> 7;                  // row 0..7 (128 float4 per row)
        int kk = (idx & 127) << 2;         // float offset in row
        int row = (r >> 1) * H_ + j0 + (r & 1);   // q*512 + j0 + jj
        *(float4*)&w_lds[r][kk] = *(const float4*)&W_hh[(size_t)row * H_ + kk];
    }
    __syncthreads();

    const int bl = tid & 31;    // batch lane 0..31
    const int r  = tid >> 5;    // gate-row slot 0..7
    const int q  = r >> 1, jj = r & 1;
    const int row = q * 512 + j0 + jj;

    float acc0 = 0.0f, acc1 = 0.0f;
    const float* hp = hT_in + bl;
#pragma unroll 4
    for (int k = 0; k < H_; k += 4) {
        const float4 w4 = *(const float4*)&w_lds[r][k];
        acc0 = fmaf(w4.x, hp[(k + 0) * BP],      acc0);
        acc1 = fmaf(w4.x, hp[(k + 0) * BP + 32], acc1);
        acc0 = fmaf(w4.y, hp[(k + 1) * BP],      acc0);
        acc1 = fmaf(w4.y, hp[(k + 1) * BP + 32], acc1);
        acc0 = fmaf(w4.z, hp[(k + 2) * BP],      acc0);
        acc1 = fmaf(w4.z, hp[(k + 2) * BP + 32], acc1);
        acc0 = fmaf(w4.w, hp[(k + 3) * BP],      acc0);
        acc1 = fmaf(w4.w, hp[(k + 3) * BP + 32], acc1);
    }

    float x0 = xg[((size_t)bl * T_ + t) * NG_ + row];
    float x1 = (bl + 32 < B_) ? xg[((size_t)(bl + 32) * T_ + t) * NG_ + row] : 0.0f;
    g_lds[r][bl]      = acc0 + x0;
    g_lds[r][bl + 32] = acc1 + x1;
    __syncthreads();

    if (tid < 128) {
        int jj2 = tid >> 6;      // 0..1
        int b   = tid & 63;
        int j   = j0 + jj2;
        if (b < B_) {
            float iv = g_lds[0 + jj2][b];
            float fv = g_lds[2 + jj2][b];
            float gv = g_lds[4 + jj2][b];
            float ov = g_lds[6 + jj2][b];
            float c_old = cT[j * BP + b];
            float cn = sigmf(fv) * c_old + sigmf(iv) * tanh_fast(gv);
            float hn = sigmf(ov) * tanh_fast(cn);
            cT[j * BP + b] = cn;
            hT_out[j * BP + b] = hn;
            if (hs) hs[((size_t)b * T_ + t) * H_ + j] = hn;
        } else {
            hT_out[j * BP + b] = 0.0f;   // keep pad lanes clean
        }
    }
}

// ---------------------------------------------------------------------------
// head: out[b][o] = lin2_b[o] + sum_u tanh(lin1_b[u]+sum_j h[b][j] lin1_W[u][j]) lin2_W[o][u]
// ---------------------------------------------------------------------------
__global__ __launch_bounds__(512) void head(
    const float* __restrict__ hT, const float* __restrict__ lin1_W,
    const float* __restrict__ lin1_b, const float* __restrict__ lin2_W,
    const float* __restrict__ lin2_b, float* __restrict__ out) {
    __shared__ float zs[B_][10];
    int tid = threadIdx.x;
    if (tid < B_ * 10) {
        int b = tid / 10, u = tid % 10;
        float acc = lin1_b[u];
        for (int j = 0; j < H_; ++j)
            acc = fmaf(hT[j * BP + b], lin1_W[u * H_ + j], acc);
        zs[b][u] = tanh_fast(acc);
    }
    __syncthreads();
    if (tid < B_ * 2) {
        int b = tid >> 1, o = tid & 1;
        float acc = lin2_b[o];
#pragma unroll
        for (int u = 0; u < 10; ++u)
            acc = fmaf(zs[b][u], lin2_W[o * 10 + u], acc);
        out[b * 2 + o] = acc;
    }
}

// ---------------------------------------------------------------------------
extern "C" void kernel_launch(void* const* d_in, const int* in_sizes, int n_in,
                              void* d_out, int out_size, void* d_ws, size_t ws_size,
                              hipStream_t stream) {
    const float* input  = (const float*)d_in[0];
    const float* pca_W  = (const float*)d_in[1];
    const float* pca_b  = (const float*)d_in[2];
    const float* W_ih0  = (const float*)d_in[3];
    const float* W_hh0  = (const float*)d_in[4];
    const float* b0     = (const float*)d_in[5];
    const float* W_ih1  = (const float*)d_in[6];
    const float* W_hh1  = (const float*)d_in[7];
    const float* b1     = (const float*)d_in[8];
    const float* h0     = (const float*)d_in[9];
    const float* c0     = (const float*)d_in[10];
    const float* lin1_W = (const float*)d_in[11];
    const float* lin1_b = (const float*)d_in[12];
    const float* lin2_W = (const float*)d_in[13];
    const float* lin2_b = (const float*)d_in[14];
    float* out = (float*)d_out;

    float* ws = (float*)d_ws;
    size_t off = 0;
    float* xg   = ws + off; off += (size_t)B_ * T_ * NG_;  // 52.4M floats
    float* xbuf = ws + off; off += (size_t)B_ * T_ * H_;   // 13.1M floats
    float* hs0  = xbuf;                                    // alias: xbuf dead before hs0 born
    float* hT0  = ws + off; off += H_ * BP;
    float* hT1  = ws + off; off += H_ * BP;
    float* cT   = ws + off; off += H_ * BP;

    const int M = B_ * T_;  // 25600

    // 1. pca: xbuf = input @ pca_W^T + pca_b   (M x 512, K=1024)
    {
        dim3 g(H_ / 128, M / 128);
        gemm_bias<<<g, 256, 0, stream>>>(input, pca_W, pca_b, xbuf, M, H_, I_);
    }
    // 2. xg0 = xbuf @ W_ih0^T + b0             (M x 2048, K=512)
    {
        dim3 g(NG_ / 128, M / 128);
        gemm_bias<<<g, 256, 0, stream>>>(xbuf, W_ih0, b0, xg, M, NG_, H_);
    }
    // 3. layer-0 scan (writes hs0)
    init_state<<<(H_ * BP) / 256, 256, 0, stream>>>(h0, c0, hT0, cT);
    float* bufs[2] = {hT0, hT1};
    for (int t = 0; t < T_; ++t)
        lstm_step<<<256, 256, 0, stream>>>(xg, bufs[t & 1], bufs[(t + 1) & 1], cT,
                                           W_hh0, hs0, t);
    // 4. xg1 = hs0 @ W_ih1^T + b1
    {
        dim3 g(NG_ / 128, M / 128);
        gemm_bias<<<g, 256, 0, stream>>>(hs0, W_ih1, b1, xg, M, NG_, H_);
    }
    // 5. layer-1 scan (no hs store; final h survives in bufs[0] since T even)
    init_state<<<(H_ * BP) / 256, 256, 0, stream>>>(h0 + B_ * H_, c0 + B_ * H_, hT0, cT);
    for (int t = 0; t < T_; ++t)
        lstm_step<<<256, 256, 0, stream>>>(xg, bufs[t & 1], bufs[(t + 1) & 1], cT,
                                           W_hh1, nullptr, t);
    // 6. head
    head<<<1, 512, 0, stream>>>(hT0, lin1_W, lin1_b, lin2_W, lin2_b, out);
}